// Round 21
// baseline (194.627 us; speedup 1.0000x reference)
//
#include <hip/hip_runtime.h>
#include <hip/hip_bf16.h>

#define N_NODES 50000
#define N_EDGES 800000
#define IN_DIM  256
#define OUT_DIM 64
#define CHUNKE  4096   // edges per radix chunk
#define NCHK    196    // ceil(800000/4096)
#define NBKT    196    // node buckets of 256
#define STAGE   12288  // LDS-staged CSR slice (ints)
#define NP      8      // src-range partitions per node list (src>>13)

using bf16x8 = __attribute__((ext_vector_type(8))) __bf16;
using f32x4  = __attribute__((ext_vector_type(4))) float;
using u32x4  = __attribute__((ext_vector_type(4))) unsigned int;

// Edge record: bin(8) | src(16) | dstlow(8).
#define EPACK(s, d)   ((unsigned)((d) >> 8) << 24 | (unsigned)(s) << 8 | ((d) & 255))
#define E_BIN(p)      ((p) >> 24)
#define E_SRC(p)      (((p) >> 8) & 0xFFFFu)
#define E_DLOW(p)     ((p) & 255u)

union BFu { u32x4 u; bf16x8 b; };

__device__ __forceinline__ void split_pack(float x0, float x1,
                                           unsigned& hi, unsigned& lo) {
    unsigned u0 = __float_as_uint(x0), u1 = __float_as_uint(x1);
    hi = (u1 & 0xFFFF0000u) | (u0 >> 16);
    float h0 = __uint_as_float(u0 & 0xFFFF0000u);
    float h1 = __uint_as_float(u1 & 0xFFFF0000u);
    unsigned r0 = __float_as_uint(x0 - h0);
    unsigned r1 = __float_as_uint(x1 - h1);
    lo = (r1 & 0xFFFF0000u) | (r0 >> 16);
}

__device__ __forceinline__ unsigned short bf16_rn(float x) {
    unsigned u = __float_as_uint(x);
    unsigned r = u + 0x7FFFu + ((u >> 16) & 1u);
    return (unsigned short)(r >> 16);
}

__device__ __forceinline__ float bf2f(unsigned short u) {
    return __uint_as_float((unsigned)u << 16);
}

// ---------------------------------------------------------------------------
// MFMA split-bf16 GEMM, A LDS-staged double-buffered.
// H output stored COLUMN-BLOCKED bf16: Hb[half][N_NODES][32] (half = col>>5)
// so each agg half-dispatch gathers from a 3.2 MB block that fits per-XCD L2.
// ---------------------------------------------------------------------------
template <int K>
__device__ __forceinline__ void gemm_body(int gbid, const float* __restrict__ X,
                                          const float* __restrict__ W,
                                          unsigned short* __restrict__ H,
                                          char* lds) {
    constexpr int NS = K / 32;
    const int lane = threadIdx.x & 63;
    const int wave = threadIdx.x >> 6;
    const int lm   = lane & 15;
    const int kg   = lane >> 4;

    BFu bhi[NS], blo[NS];
#pragma unroll
    for (int s = 0; s < NS; ++s) {
#pragma unroll
        for (int jp = 0; jp < 4; ++jp) {
            float w0 = W[(size_t)(s * 32 + kg * 8 + 2 * jp)     * 64 + wave * 16 + lm];
            float w1 = W[(size_t)(s * 32 + kg * 8 + 2 * jp + 1) * 64 + wave * 16 + lm];
            unsigned h, l;
            split_pack(w0, w1, h, l);
            bhi[s].u[jp] = h;
            blo[s].u[jp] = l;
        }
    }

    const int srow = threadIdx.x >> 2;
    const int skc  = (threadIdx.x & 3) * 8;
    int gr = gbid * 64 + srow;
    const float* xs = X + (size_t)((gr < N_NODES) ? gr : (N_NODES - 1)) * K;

    f32x4 acc[4] = {};

    float4 c0 = *(const float4*)(xs + skc);
    float4 c1 = *(const float4*)(xs + skc + 4);

#pragma unroll
    for (int s = 0; s < NS; ++s) {
        unsigned short* a_hi = (unsigned short*)(lds + (s & 1) * 8192);
        unsigned short* a_lo = a_hi + 64 * 32;

        BFu h_, l_;
        unsigned h, l;
        split_pack(c0.x, c0.y, h, l); h_.u[0] = h; l_.u[0] = l;
        split_pack(c0.z, c0.w, h, l); h_.u[1] = h; l_.u[1] = l;
        split_pack(c1.x, c1.y, h, l); h_.u[2] = h; l_.u[2] = l;
        split_pack(c1.z, c1.w, h, l); h_.u[3] = h; l_.u[3] = l;
        *(u32x4*)(a_hi + srow * 32 + skc) = h_.u;
        *(u32x4*)(a_lo + srow * 32 + skc) = l_.u;

        if (s + 1 < NS) {
            c0 = *(const float4*)(xs + (s + 1) * 32 + skc);
            c1 = *(const float4*)(xs + (s + 1) * 32 + skc + 4);
        }

        __syncthreads();

#pragma unroll
        for (int m = 0; m < 4; ++m) {
            BFu ah, al;
            ah.u = *(const u32x4*)(a_hi + (m * 16 + lm) * 32 + kg * 8);
            al.u = *(const u32x4*)(a_lo + (m * 16 + lm) * 32 + kg * 8);
            acc[m] = __builtin_amdgcn_mfma_f32_16x16x32_bf16(ah.b, bhi[s].b, acc[m], 0, 0, 0);
            acc[m] = __builtin_amdgcn_mfma_f32_16x16x32_bf16(ah.b, blo[s].b, acc[m], 0, 0, 0);
            acc[m] = __builtin_amdgcn_mfma_f32_16x16x32_bf16(al.b, bhi[s].b, acc[m], 0, 0, 0);
        }
    }

    const int c    = wave * 16 + lm;
    const int half = c >> 5;
    const int c32  = c & 31;
#pragma unroll
    for (int m = 0; m < 4; ++m) {
#pragma unroll
        for (int t = 0; t < 4; ++t) {
            int r = gbid * 64 + m * 16 + kg * 4 + t;
            if (r < N_NODES)
                H[((size_t)half * N_NODES + r) * 32 + c32] = bf16_rn(acc[m][t]);
        }
    }
}

// ---------------------------------------------------------------------------
// Fused R1 + layer-1 GEMM (disjoint block ranges).
// ---------------------------------------------------------------------------
template <int K>
__global__ __launch_bounds__(256) void fused_hist_gemm1(const void* __restrict__ edges,
                                                        unsigned* __restrict__ epack,
                                                        int* __restrict__ hist,
                                                        const float* __restrict__ X,
                                                        const float* __restrict__ W,
                                                        unsigned short* __restrict__ H) {
    __shared__ char lds[16384];
    if ((int)blockIdx.x < NCHK) {
        int* h  = (int*)lds;
        int* nz = (int*)(lds + 1024);
        if (threadIdx.x == 0) *nz = 0;
        h[threadIdx.x] = 0;
        __syncthreads();
        if (((const unsigned int*)edges)[2 * threadIdx.x + 1] != 0u) *nz = 1;
        __syncthreads();
        const int is64 = (*nz == 0);
        const int base = blockIdx.x * CHUNKE;
        for (int i = threadIdx.x; i < CHUNKE; i += 256) {
            int e = base + i;
            if (e < N_EDGES) {
                int s, d;
                if (is64) {
                    s = (int)((const long long*)edges)[e];
                    d = (int)((const long long*)edges)[(long long)N_EDGES + e];
                } else {
                    s = ((const int*)edges)[e];
                    d = ((const int*)edges)[(long long)N_EDGES + e];
                }
                epack[e] = EPACK(s, d);
                atomicAdd(&h[d >> 8], 1);
            }
        }
        __syncthreads();
        hist[blockIdx.x * 256 + threadIdx.x] = h[threadIdx.x];
    } else {
        gemm_body<K>((int)blockIdx.x - NCHK, X, W, H, lds);
    }
}

// ---------------------------------------------------------------------------
// R2: per-bin exclusive scan over chunks (in place); bsum[b] = bin total.
// ---------------------------------------------------------------------------
__global__ __launch_bounds__(64) void radix_scan(int* __restrict__ hist,
                                                 int* __restrict__ bsum) {
    const int b = blockIdx.x, l = threadIdx.x;
    int carry = 0;
#pragma unroll
    for (int seg = 0; seg < 4; ++seg) {
        int c = seg * 64 + l;
        int v = (c < NCHK) ? hist[c * 256 + b] : 0;
        int incl = v;
        for (int s = 1; s < 64; s <<= 1) {
            int t = __shfl_up(incl, s);
            if (l >= s) incl += t;
        }
        if (c < NCHK) hist[c * 256 + b] = incl - v + carry;
        carry += __shfl(incl, 63);
    }
    if (l == 0) bsum[b] = carry;
}

// ---------------------------------------------------------------------------
// R4: scatter packed records to bucket-sorted order.
// ---------------------------------------------------------------------------
__global__ __launch_bounds__(256) void radix_scatter(const unsigned* __restrict__ epack,
                                                     const int* __restrict__ hist,
                                                     const int* __restrict__ bsum,
                                                     unsigned* __restrict__ ebuf) {
    __shared__ int lcur[256];
    __shared__ int sm[256];
    __shared__ int sbase[256];
    const int t = threadIdx.x;
    int v = bsum[t];
    sm[t] = v;
    lcur[t] = 0;
    __syncthreads();
    for (int s = 1; s < 256; s <<= 1) {
        int tv = 0;
        if (t >= s) tv = sm[t - s];
        __syncthreads();
        if (t >= s) sm[t] += tv;
        __syncthreads();
    }
    sbase[t] = sm[t] - v;
    __syncthreads();
    const int base = blockIdx.x * CHUNKE;
    for (int i = t; i < CHUNKE; i += 256) {
        int e = base + i;
        if (e < N_EDGES) {
            unsigned p = epack[e];
            int bin = (int)E_BIN(p);
            int loc = atomicAdd(&lcur[bin], 1);
            int pos = sbase[bin] + hist[blockIdx.x * 256 + bin] + loc;
            ebuf[pos] = p;
        }
    }
}

// ---------------------------------------------------------------------------
// R5: per-bucket finalize: off/dinv + LDS-staged coalesced CSR slice.
// ---------------------------------------------------------------------------
__global__ __launch_bounds__(256) void bucket_finalize(const unsigned* __restrict__ ebuf,
                                                       const int* __restrict__ bsum,
                                                       float* __restrict__ dinv,
                                                       int* __restrict__ off,
                                                       int* __restrict__ csr_src) {
    __shared__ int hist[256];
    __shared__ int sm[256];
    __shared__ int histp[NP * 256];
    __shared__ int curp[NP * 256];
    __shared__ int stage[STAGE];
    __shared__ int beg_s, end_s;
    const int b = blockIdx.x, t = threadIdx.x;

    int v = bsum[t];
    sm[t] = v;
    __syncthreads();
    for (int s = 1; s < 256; s <<= 1) {
        int tv = 0;
        if (t >= s) tv = sm[t - s];
        __syncthreads();
        if (t >= s) sm[t] += tv;
        __syncthreads();
    }
    if (t == b) { beg_s = sm[t] - v; end_s = sm[t]; }
    __syncthreads();
    const int beg = beg_s, end = end_s, size = end - beg;

    hist[t] = 0;
#pragma unroll
    for (int p = 0; p < NP; ++p) histp[p * 256 + t] = 0;
    __syncthreads();
    for (int e = beg + t; e < end; e += 256) {
        unsigned pk = ebuf[e];
        atomicAdd(&hist[E_DLOW(pk)], 1);
        atomicAdd(&histp[(E_SRC(pk) >> 13) * 256 + E_DLOW(pk)], 1);
    }
    __syncthreads();

    v = hist[t];
    sm[t] = v;
    __syncthreads();
    for (int s = 1; s < 256; s <<= 1) {
        int tv = 0;
        if (t >= s) tv = sm[t - s];
        __syncthreads();
        if (t >= s) sm[t] += tv;
        __syncthreads();
    }
    int pre = sm[t] - v;

    int node = b * 256 + t;
    if (node < N_NODES) {
        off[node] = beg + pre;
        dinv[node] = rsqrtf((float)(v + 1));
    }
    if (b == NBKT - 1 && t == 0) off[N_NODES] = end;

    {
        int running = pre;
#pragma unroll
        for (int p = 0; p < NP; ++p) {
            curp[p * 256 + t] = running;
            running += histp[p * 256 + t];
        }
    }
    __syncthreads();

    if (size <= STAGE) {
        for (int e = beg + t; e < end; e += 256) {
            unsigned pk = ebuf[e];
            int q = atomicAdd(&curp[(E_SRC(pk) >> 13) * 256 + E_DLOW(pk)], 1);
            stage[q] = (int)E_SRC(pk);
        }
        __syncthreads();
        for (int i = t; i < size; i += 256) csr_src[beg + i] = stage[i];
    } else {
        for (int e = beg + t; e < end; e += 256) {
            unsigned pk = ebuf[e];
            int q = atomicAdd(&curp[(E_SRC(pk) >> 13) * 256 + E_DLOW(pk)], 1);
            csr_src[beg + q] = (int)E_SRC(pk);
        }
    }
}

template <int K>
__global__ __launch_bounds__(256) void gemm_mfma(const float* __restrict__ X,
                                                 const float* __restrict__ W,
                                                 unsigned short* __restrict__ H) {
    __shared__ char lds[16384];
    gemm_body<K>((int)blockIdx.x, X, W, H, lds);
}

// ---------------------------------------------------------------------------
// Half-column gather-aggregate: one dispatch per 32-col half of H (3.2 MB,
// per-XCD-L2-resident). Wave = 1 node; lane = (edge parity (>>5), col (&31)).
// Two edges processed per iteration; parities merged via shfl_xor(32).
// out = relu( (Σ_s Hh[s]*dinv[s] + Hh[d]*dd) * dd + b )   (cols half*32..+32)
// ---------------------------------------------------------------------------
__global__ __launch_bounds__(256) void agg_half(const unsigned short* __restrict__ H_all,
                                                const float* __restrict__ dinv,
                                                const float* __restrict__ b,
                                                const int* __restrict__ off,
                                                const int* __restrict__ csr_src,
                                                float* __restrict__ out,
                                                int half) {
    int wid  = (blockIdx.x * 256 + threadIdx.x) >> 6;
    int lane = threadIdx.x & 63;
    if (wid >= N_NODES) return;
    const int col = lane & 31;
    const int eh  = lane >> 5;
    const unsigned short* Hh = H_all + (size_t)half * N_NODES * 32;

    float dd = dinv[wid];
    float acc = 0.f;
    int beg = off[wid], end = off[wid + 1];
    for (int k0 = beg; k0 < end; k0 += 64) {
        int myk = k0 + lane;
        int   s_l  = (myk < end) ? csr_src[myk] : 0;
        float ds_l = (myk < end) ? dinv[s_l] : 0.f;   // 0 for pad -> safe
#pragma unroll
        for (int jb = 0; jb < 4; ++jb) {
            float v[8], nm[8];
#pragma unroll
            for (int jj = 0; jj < 8; ++jj) {
                int eidx = 2 * (jb * 8 + jj) + eh;
                int s  = __shfl(s_l, eidx);
                nm[jj] = __shfl(ds_l, eidx);
                v[jj]  = bf2f(Hh[(size_t)s * 32 + col]);
            }
#pragma unroll
            for (int jj = 0; jj < 8; ++jj) acc = fmaf(v[jj], nm[jj], acc);
        }
    }
    float red = acc + __shfl_xor(acc, 32);
    float sv  = bf2f(Hh[(size_t)wid * 32 + col]);
    float tot = fmaf(sv, dd, red);
    if (lane < 32)
        out[(size_t)wid * 64 + half * 32 + col] =
            fmaxf(fmaf(tot, dd, b[half * 32 + col]), 0.f);
}

extern "C" void kernel_launch(void* const* d_in, const int* in_sizes, int n_in,
                              void* d_out, int out_size, void* d_ws, size_t ws_size,
                              hipStream_t stream) {
    const float* feat = (const float*)d_in[0];
    const float* W1   = (const float*)d_in[1];
    const float* b1   = (const float*)d_in[2];
    const float* W2   = (const float*)d_in[3];
    const float* b2   = (const float*)d_in[4];
    const void*  edges = d_in[5];
    float* out = (float*)d_out;

    char* ws = (char*)d_ws;
    const size_t SZ_E = (size_t)N_EDGES * 4;
    int*      bsum    = (int*)(ws + 2048);
    int*      hist    = (int*)(ws + 4096);
    float*    dinv    = (float*)(ws + 4096 + 204800);
    int*      off     = (int*)(ws + 4096 + 2 * 204800);
    size_t o = 4096 + 3 * 204800;
    unsigned* epack   = (unsigned*)(ws + o);      o += SZ_E;
    unsigned* ebuf    = (unsigned*)(ws + o);      o += SZ_E;
    int*      csr_src = (int*)(ws + o);           o += SZ_E;
    unsigned short* H = (unsigned short*)(ws + o);               // 6.4 MB blocked

    const int NB_G = (N_NODES + 63) / 64;         // 782
    const int NB_W = (N_NODES * 64 + 255) / 256;  // 12500

    fused_hist_gemm1<IN_DIM><<<NCHK + NB_G, 256, 0, stream>>>(
        edges, epack, hist, feat, W1, H);
    radix_scan<<<256, 64, 0, stream>>>(hist, bsum);
    radix_scatter<<<NCHK, 256, 0, stream>>>(epack, hist, bsum, ebuf);
    bucket_finalize<<<NBKT, 256, 0, stream>>>(ebuf, bsum, dinv, off, csr_src);

    // Layer 1 aggregate (z1 f32), one dispatch per H column-half.
    agg_half<<<NB_W, 256, 0, stream>>>(H, dinv, b1, off, csr_src, out, 0);
    agg_half<<<NB_W, 256, 0, stream>>>(H, dinv, b1, off, csr_src, out, 1);

    // Layer 2 (out holds relu'd z1; H reused, blocked layout).
    gemm_mfma<OUT_DIM><<<NB_G, 256, 0, stream>>>(out, W2, H);
    agg_half<<<NB_W, 256, 0, stream>>>(H, dinv, b2, off, csr_src, out, 0);
    agg_half<<<NB_W, 256, 0, stream>>>(H, dinv, b2, off, csr_src, out, 1);
}

// Round 22
// 112.835 us; speedup vs baseline: 1.7249x; 1.7249x over previous
//
#include <hip/hip_runtime.h>
#include <hip/hip_bf16.h>

#define N_NODES 50000
#define N_EDGES 800000
#define IN_DIM  256
#define OUT_DIM 64
#define CHUNKE  4096   // edges per radix chunk
#define NCHK    196    // ceil(800000/4096)
#define NBKT    196    // node buckets of 256
#define STAGE   12288  // LDS-staged CSR slice (ints)

using bf16x8 = __attribute__((ext_vector_type(8))) __bf16;
using f32x4  = __attribute__((ext_vector_type(4))) float;
using u32x4  = __attribute__((ext_vector_type(4))) unsigned int;

// Edge record: bin(8) | src(16) | dstlow(8).  bin = dst>>8 (<196), src < 50000
// < 2^16, dstlow = dst & 255.  Node id = bin*256 + dstlow.
#define EPACK(s, d)   ((unsigned)((d) >> 8) << 24 | (unsigned)(s) << 8 | ((d) & 255))
#define E_BIN(p)      ((p) >> 24)
#define E_SRC(p)      (((p) >> 8) & 0xFFFFu)
#define E_DLOW(p)     ((p) & 255u)

union BFu { u32x4 u; bf16x8 b; };

__device__ __forceinline__ void split_pack(float x0, float x1,
                                           unsigned& hi, unsigned& lo) {
    unsigned u0 = __float_as_uint(x0), u1 = __float_as_uint(x1);
    hi = (u1 & 0xFFFF0000u) | (u0 >> 16);
    float h0 = __uint_as_float(u0 & 0xFFFF0000u);
    float h1 = __uint_as_float(u1 & 0xFFFF0000u);
    unsigned r0 = __float_as_uint(x0 - h0);
    unsigned r1 = __float_as_uint(x1 - h1);
    lo = (r1 & 0xFFFF0000u) | (r0 >> 16);
}

__device__ __forceinline__ unsigned short bf16_rn(float x) {
    unsigned u = __float_as_uint(x);
    unsigned r = u + 0x7FFFu + ((u >> 16) & 1u);
    return (unsigned short)(r >> 16);
}

__device__ __forceinline__ float bf2f(unsigned short u) {
    return __uint_as_float((unsigned)u << 16);
}

// ---------------------------------------------------------------------------
// MFMA split-bf16 GEMM, A LDS-staged double-buffered, H out bf16.
// ---------------------------------------------------------------------------
template <int K>
__device__ __forceinline__ void gemm_body(int gbid, const float* __restrict__ X,
                                          const float* __restrict__ W,
                                          unsigned short* __restrict__ H,
                                          char* lds) {
    constexpr int NS = K / 32;
    const int lane = threadIdx.x & 63;
    const int wave = threadIdx.x >> 6;
    const int lm   = lane & 15;
    const int kg   = lane >> 4;

    BFu bhi[NS], blo[NS];
#pragma unroll
    for (int s = 0; s < NS; ++s) {
#pragma unroll
        for (int jp = 0; jp < 4; ++jp) {
            float w0 = W[(size_t)(s * 32 + kg * 8 + 2 * jp)     * 64 + wave * 16 + lm];
            float w1 = W[(size_t)(s * 32 + kg * 8 + 2 * jp + 1) * 64 + wave * 16 + lm];
            unsigned h, l;
            split_pack(w0, w1, h, l);
            bhi[s].u[jp] = h;
            blo[s].u[jp] = l;
        }
    }

    const int srow = threadIdx.x >> 2;
    const int skc  = (threadIdx.x & 3) * 8;
    int gr = gbid * 64 + srow;
    const float* xs = X + (size_t)((gr < N_NODES) ? gr : (N_NODES - 1)) * K;

    f32x4 acc[4] = {};

    float4 c0 = *(const float4*)(xs + skc);
    float4 c1 = *(const float4*)(xs + skc + 4);

#pragma unroll
    for (int s = 0; s < NS; ++s) {
        unsigned short* a_hi = (unsigned short*)(lds + (s & 1) * 8192);
        unsigned short* a_lo = a_hi + 64 * 32;

        BFu h_, l_;
        unsigned h, l;
        split_pack(c0.x, c0.y, h, l); h_.u[0] = h; l_.u[0] = l;
        split_pack(c0.z, c0.w, h, l); h_.u[1] = h; l_.u[1] = l;
        split_pack(c1.x, c1.y, h, l); h_.u[2] = h; l_.u[2] = l;
        split_pack(c1.z, c1.w, h, l); h_.u[3] = h; l_.u[3] = l;
        *(u32x4*)(a_hi + srow * 32 + skc) = h_.u;
        *(u32x4*)(a_lo + srow * 32 + skc) = l_.u;

        if (s + 1 < NS) {
            c0 = *(const float4*)(xs + (s + 1) * 32 + skc);
            c1 = *(const float4*)(xs + (s + 1) * 32 + skc + 4);
        }

        __syncthreads();

#pragma unroll
        for (int m = 0; m < 4; ++m) {
            BFu ah, al;
            ah.u = *(const u32x4*)(a_hi + (m * 16 + lm) * 32 + kg * 8);
            al.u = *(const u32x4*)(a_lo + (m * 16 + lm) * 32 + kg * 8);
            acc[m] = __builtin_amdgcn_mfma_f32_16x16x32_bf16(ah.b, bhi[s].b, acc[m], 0, 0, 0);
            acc[m] = __builtin_amdgcn_mfma_f32_16x16x32_bf16(ah.b, blo[s].b, acc[m], 0, 0, 0);
            acc[m] = __builtin_amdgcn_mfma_f32_16x16x32_bf16(al.b, bhi[s].b, acc[m], 0, 0, 0);
        }
    }

    const int c = wave * 16 + lm;
#pragma unroll
    for (int m = 0; m < 4; ++m) {
#pragma unroll
        for (int t = 0; t < 4; ++t) {
            int r = gbid * 64 + m * 16 + kg * 4 + t;
            if (r < N_NODES) H[(size_t)r * 64 + c] = bf16_rn(acc[m][t]);
        }
    }
}

// ---------------------------------------------------------------------------
// Fused R1 + layer-1 GEMM: blocks [0,NCHK) normalize edges to packed 4B
// records + per-chunk 256-bin histogram; the rest run gemm1.
// ---------------------------------------------------------------------------
template <int K>
__global__ __launch_bounds__(256) void fused_hist_gemm1(const void* __restrict__ edges,
                                                        unsigned* __restrict__ epack,
                                                        int* __restrict__ hist,
                                                        const float* __restrict__ X,
                                                        const float* __restrict__ W,
                                                        unsigned short* __restrict__ H) {
    __shared__ char lds[16384];
    if ((int)blockIdx.x < NCHK) {
        int* h  = (int*)lds;
        int* nz = (int*)(lds + 1024);
        if (threadIdx.x == 0) *nz = 0;
        h[threadIdx.x] = 0;
        __syncthreads();
        if (((const unsigned int*)edges)[2 * threadIdx.x + 1] != 0u) *nz = 1;
        __syncthreads();
        const int is64 = (*nz == 0);
        const int base = blockIdx.x * CHUNKE;
        for (int i = threadIdx.x; i < CHUNKE; i += 256) {
            int e = base + i;
            if (e < N_EDGES) {
                int s, d;
                if (is64) {
                    s = (int)((const long long*)edges)[e];
                    d = (int)((const long long*)edges)[(long long)N_EDGES + e];
                } else {
                    s = ((const int*)edges)[e];
                    d = ((const int*)edges)[(long long)N_EDGES + e];
                }
                epack[e] = EPACK(s, d);
                atomicAdd(&h[d >> 8], 1);
            }
        }
        __syncthreads();
        hist[blockIdx.x * 256 + threadIdx.x] = h[threadIdx.x];
    } else {
        gemm_body<K>((int)blockIdx.x - NCHK, X, W, H, lds);
    }
}

// ---------------------------------------------------------------------------
// R2: per-bin exclusive scan over chunks (in place); bsum[b] = bin total.
// ---------------------------------------------------------------------------
__global__ __launch_bounds__(64) void radix_scan(int* __restrict__ hist,
                                                 int* __restrict__ bsum) {
    const int b = blockIdx.x, l = threadIdx.x;
    int carry = 0;
#pragma unroll
    for (int seg = 0; seg < 4; ++seg) {
        int c = seg * 64 + l;
        int v = (c < NCHK) ? hist[c * 256 + b] : 0;
        int incl = v;
        for (int s = 1; s < 64; s <<= 1) {
            int t = __shfl_up(incl, s);
            if (l >= s) incl += t;
        }
        if (c < NCHK) hist[c * 256 + b] = incl - v + carry;
        carry += __shfl(incl, 63);
    }
    if (l == 0) bsum[b] = carry;
}

// ---------------------------------------------------------------------------
// R4: scatter packed records to bucket-sorted order.
// ---------------------------------------------------------------------------
__global__ __launch_bounds__(256) void radix_scatter(const unsigned* __restrict__ epack,
                                                     const int* __restrict__ hist,
                                                     const int* __restrict__ bsum,
                                                     unsigned* __restrict__ ebuf) {
    __shared__ int lcur[256];
    __shared__ int sm[256];
    __shared__ int sbase[256];
    const int t = threadIdx.x;
    int v = bsum[t];
    sm[t] = v;
    lcur[t] = 0;
    __syncthreads();
    for (int s = 1; s < 256; s <<= 1) {
        int tv = 0;
        if (t >= s) tv = sm[t - s];
        __syncthreads();
        if (t >= s) sm[t] += tv;
        __syncthreads();
    }
    sbase[t] = sm[t] - v;
    __syncthreads();
    const int base = blockIdx.x * CHUNKE;
    for (int i = t; i < CHUNKE; i += 256) {
        int e = base + i;
        if (e < N_EDGES) {
            unsigned p = epack[e];
            int bin = (int)E_BIN(p);
            int loc = atomicAdd(&lcur[bin], 1);
            int pos = sbase[bin] + hist[blockIdx.x * 256 + bin] + loc;
            ebuf[pos] = p;
        }
    }
}

// ---------------------------------------------------------------------------
// R5: per-bucket finalize: off/dinv + LDS-staged coalesced CSR slice.
// ---------------------------------------------------------------------------
__global__ __launch_bounds__(256) void bucket_finalize(const unsigned* __restrict__ ebuf,
                                                       const int* __restrict__ bsum,
                                                       float* __restrict__ dinv,
                                                       int* __restrict__ off,
                                                       int* __restrict__ csr_src) {
    __shared__ int hist[256];
    __shared__ int sm[256];
    __shared__ int cur[256];
    __shared__ int stage[STAGE];
    __shared__ int beg_s, end_s;
    const int b = blockIdx.x, t = threadIdx.x;

    int v = bsum[t];
    sm[t] = v;
    __syncthreads();
    for (int s = 1; s < 256; s <<= 1) {
        int tv = 0;
        if (t >= s) tv = sm[t - s];
        __syncthreads();
        if (t >= s) sm[t] += tv;
        __syncthreads();
    }
    if (t == b) { beg_s = sm[t] - v; end_s = sm[t]; }
    __syncthreads();
    const int beg = beg_s, end = end_s, size = end - beg;

    hist[t] = 0;
    __syncthreads();
    for (int e = beg + t; e < end; e += 256)
        atomicAdd(&hist[E_DLOW(ebuf[e])], 1);
    __syncthreads();

    v = hist[t];
    sm[t] = v;
    __syncthreads();
    for (int s = 1; s < 256; s <<= 1) {
        int tv = 0;
        if (t >= s) tv = sm[t - s];
        __syncthreads();
        if (t >= s) sm[t] += tv;
        __syncthreads();
    }
    int pre = sm[t] - v;

    int node = b * 256 + t;
    if (node < N_NODES) {
        off[node] = beg + pre;
        dinv[node] = rsqrtf((float)(v + 1));
    }
    if (b == NBKT - 1 && t == 0) off[N_NODES] = end;

    cur[t] = pre;
    __syncthreads();

    if (size <= STAGE) {
        for (int e = beg + t; e < end; e += 256) {
            unsigned p = ebuf[e];
            int q = atomicAdd(&cur[E_DLOW(p)], 1);
            stage[q] = (int)E_SRC(p);
        }
        __syncthreads();
        for (int i = t; i < size; i += 256) csr_src[beg + i] = stage[i];
    } else {
        for (int e = beg + t; e < end; e += 256) {
            unsigned p = ebuf[e];
            int q = atomicAdd(&cur[E_DLOW(p)], 1);
            csr_src[beg + q] = (int)E_SRC(p);
        }
    }
}

template <int K>
__global__ __launch_bounds__(256) void gemm_mfma(const float* __restrict__ X,
                                                 const float* __restrict__ W,
                                                 unsigned short* __restrict__ H) {
    __shared__ char lds[16384];
    gemm_body<K>((int)blockIdx.x, X, W, H, lds);
}

// ---------------------------------------------------------------------------
// Gather-aggregate: one wave per dst node, lane = column. H bf16, f32 accum.
// out = relu( (Σ_s H[s]*dinv[s] + H[d]*dd) * dd + b )
// ---------------------------------------------------------------------------
__global__ __launch_bounds__(256) void agg_csr(const unsigned short* __restrict__ H,
                                               const float* __restrict__ dinv,
                                               const float* __restrict__ b,
                                               const int* __restrict__ off,
                                               const int* __restrict__ csr_src,
                                               float* __restrict__ out) {
    int wid  = (blockIdx.x * 256 + threadIdx.x) >> 6;
    int lane = threadIdx.x & 63;
    if (wid >= N_NODES) return;
    float dd = dinv[wid];
    float acc = bf2f(H[(size_t)wid * 64 + lane]) * dd;
    int beg = off[wid], end = off[wid + 1];
    for (int k0 = beg; k0 < end; k0 += 64) {
        int myk = k0 + lane;
        int   s_l  = (myk < end) ? csr_src[myk] : 0;
        float ds_l = (myk < end) ? dinv[s_l] : 0.f;
        int cnt = min(64, end - k0);
        int i = 0;
        for (; i + 8 <= cnt; i += 8) {
            float v[8], nm[8];
#pragma unroll
            for (int jj = 0; jj < 8; ++jj) {
                int s  = __shfl(s_l, i + jj);
                nm[jj] = __shfl(ds_l, i + jj);
                v[jj]  = bf2f(H[(size_t)s * 64 + lane]);
            }
#pragma unroll
            for (int jj = 0; jj < 8; ++jj) acc = fmaf(v[jj], nm[jj], acc);
        }
        for (; i < cnt; ++i) {
            int   s  = __shfl(s_l, i);
            float nm = __shfl(ds_l, i);
            acc = fmaf(bf2f(H[(size_t)s * 64 + lane]), nm, acc);
        }
    }
    out[(size_t)wid * 64 + lane] = fmaxf(fmaf(acc, dd, b[lane]), 0.f);
}

extern "C" void kernel_launch(void* const* d_in, const int* in_sizes, int n_in,
                              void* d_out, int out_size, void* d_ws, size_t ws_size,
                              hipStream_t stream) {
    const float* feat = (const float*)d_in[0];
    const float* W1   = (const float*)d_in[1];
    const float* b1   = (const float*)d_in[2];
    const float* W2   = (const float*)d_in[3];
    const float* b2   = (const float*)d_in[4];
    const void*  edges = d_in[5];
    float* out = (float*)d_out;

    char* ws = (char*)d_ws;
    const size_t SZ_E = (size_t)N_EDGES * 4;
    int*      bsum    = (int*)(ws + 2048);                       // 256 ints
    int*      hist    = (int*)(ws + 4096);                       // 196*256 ints
    float*    dinv    = (float*)(ws + 4096 + 204800);            // 50000 f32
    int*      off     = (int*)(ws + 4096 + 2 * 204800);          // 50001 ints
    size_t o = 4096 + 3 * 204800;
    unsigned* epack   = (unsigned*)(ws + o);      o += SZ_E;     // 3.2 MB
    unsigned* ebuf    = (unsigned*)(ws + o);      o += SZ_E;     // 3.2 MB
    int*      csr_src = (int*)(ws + o);           o += SZ_E;     // 3.2 MB
    unsigned short* H = (unsigned short*)(ws + o);               // 6.4 MB (bf16)

    const int NB_G = (N_NODES + 63) / 64;         // 782
    const int NB_W = (N_NODES * 64 + 255) / 256;  // 12500

    fused_hist_gemm1<IN_DIM><<<NCHK + NB_G, 256, 0, stream>>>(
        edges, epack, hist, feat, W1, H);
    radix_scan<<<256, 64, 0, stream>>>(hist, bsum);
    radix_scatter<<<NCHK, 256, 0, stream>>>(epack, hist, bsum, ebuf);
    bucket_finalize<<<NBKT, 256, 0, stream>>>(ebuf, bsum, dinv, off, csr_src);

    // Layer 1 aggregate (f32 out = z1).
    agg_csr<<<NB_W, 256, 0, stream>>>(H, dinv, b1, off, csr_src, out);

    // Layer 2 (out holds relu'd z1; H reused).
    gemm_mfma<OUT_DIM><<<NB_G, 256, 0, stream>>>(out, W2, H);
    agg_csr<<<NB_W, 256, 0, stream>>>(H, dinv, b2, off, csr_src, out);
}